// Round 1
// baseline (417.518 us; speedup 1.0000x reference)
//
#include <hip/hip_runtime.h>
#include <hip/hip_fp16.h>

// ---------------- problem constants ----------------
#define NNODES 100000

// ---------------- workspace layout (bytes) ----------------
#define OFF_W1TH     0UL            // _Float16[256*128] frag-order = 65536
#define OFF_W1TL     65536UL        // _Float16[256*128]
#define OFF_W2TH     131072UL       // _Float16[128*64] = 16384
#define OFF_W2TL     147456UL       // _Float16[128*64] -> ends 163840
#define OFF_BCNT     163840UL       // int[512]
#define OFF_BBASE    165888UL       // int[512]
#define OFF_BCUR     167936UL       // int[512] -> ends 169984
#define OFF_ROWPTR   400128UL       // int[100001]
#define OFF_DINV     1200640UL      // float[100000]
#define OFF_COL      1605632UL      // int[1600000]  -> ends 8005632
#define OFF_EBUF     8005632UL      // int[1600000] = 6.4MB (overlaps h1g; dead before gemm1)
#define OFF_H1G      8005632UL      // half[100000*128] = 25.6MB -> ends 33605632
#define OFF_H1OUT    59205632UL     // half[100000*128] = 25.6MB -> ends 84805632
// h2g (half[100000*64]) reuses OFF_H1G (h1g dead after agg1)

typedef __attribute__((ext_vector_type(8))) _Float16 f16x8;
typedef __attribute__((ext_vector_type(4))) float f32x4;

// async global->LDS 16B per lane (dest = wave-uniform base + lane*16)
__device__ __forceinline__ void async_copy16(void* lds, const void* g) {
    __builtin_amdgcn_global_load_lds(
        (const __attribute__((address_space(1))) unsigned*)g,
        (__attribute__((address_space(3))) unsigned*)lds, 16, 0, 0);
}

// =========== CSR build via 2-level counting sort (bucket = dst>>8) ===========
__global__ __launch_bounds__(256) void bincount(const int* __restrict__ dst,
                                                int* __restrict__ bcnt, int E) {
    __shared__ int lc[512];
    int t = threadIdx.x;
    lc[t] = 0; lc[t + 256] = 0;
    __syncthreads();
    for (int e = blockIdx.x * 256 + t; e < E; e += gridDim.x * 256)
        atomicAdd(&lc[dst[e] >> 8], 1);
    __syncthreads();
    if (lc[t]) atomicAdd(&bcnt[t], lc[t]);
    if (lc[t + 256]) atomicAdd(&bcnt[t + 256], lc[t + 256]);
}

__global__ __launch_bounds__(512) void bscan(const int* __restrict__ bcnt,
                                             int* __restrict__ bbase,
                                             int* __restrict__ bcur,
                                             int* __restrict__ rowptr,
                                             int NB, int N, int E) {
    __shared__ int s[512];
    int t = threadIdx.x;
    int v = (t < NB) ? bcnt[t] : 0;
    s[t] = v;
    __syncthreads();
    for (int off = 1; off < 512; off <<= 1) {
        int add = (t >= off) ? s[t - off] : 0;
        __syncthreads();
        s[t] += add;
        __syncthreads();
    }
    if (t < NB) {
        int ex = s[t] - v;
        bbase[t] = ex;
        bcur[t] = ex;
    }
    if (t == 0) rowptr[N] = E;
}

// Phase C: bucket-grouped scatter. Packs (src | localdst<<20) into one int.
#define CHUNK 8192
__global__ __launch_bounds__(256) void binscatter(const int* __restrict__ src,
                                                  const int* __restrict__ dst,
                                                  int* __restrict__ bcur,
                                                  int* __restrict__ ebuf, int E) {
    __shared__ int lc[512];
    __shared__ int gb[512];
    int t = threadIdx.x;
    lc[t] = 0; lc[t + 256] = 0;
    __syncthreads();
    int base = blockIdx.x * CHUNK;
    int rb[32];
#pragma unroll
    for (int i = 0; i < 32; ++i) {
        int e = base + i * 256 + t;
        if (e < E) {
            int b = dst[e] >> 8;
            rb[i] = (b << 13) | atomicAdd(&lc[b], 1);  // rank < 8192 fits 13 bits
        } else rb[i] = -1;
    }
    __syncthreads();
    if (lc[t]) gb[t] = atomicAdd(&bcur[t], lc[t]);
    if (lc[t + 256]) gb[t + 256] = atomicAdd(&bcur[t + 256], lc[t + 256]);
    __syncthreads();
#pragma unroll
    for (int i = 0; i < 32; ++i) {
        if (rb[i] >= 0) {
            int e = base + i * 256 + t;
            int b = rb[i] >> 13, r = rb[i] & 8191;
            ebuf[gb[b] + r] = src[e] | ((dst[e] & 255) << 20);
        }
    }
}

__global__ __launch_bounds__(256) void buildcsr(const int* __restrict__ ebuf,
                                                const int* __restrict__ bbase,
                                                const int* __restrict__ bcnt,
                                                int* __restrict__ rowptr,
                                                int* __restrict__ colarr,
                                                float* __restrict__ dinv, int N) {
    int b = blockIdx.x;
    int t = threadIdx.x;
    int start = bbase[b];
    int cnt = bcnt[b];
    __shared__ int nc[256];
    __shared__ int s[256];
    __shared__ int ncur[256];
    nc[t] = 0;
    __syncthreads();
    for (int e = t; e < cnt; e += 256) atomicAdd(&nc[ebuf[start + e] >> 20], 1);
    __syncthreads();
    int own = nc[t];
    s[t] = own;
    __syncthreads();
    for (int off = 1; off < 256; off <<= 1) {
        int add = (t >= off) ? s[t - off] : 0;
        __syncthreads();
        s[t] += add;
        __syncthreads();
    }
    int rowbase = start + s[t] - own;
    int n0 = b << 8;
    if (n0 + t < N) {
        rowptr[n0 + t] = rowbase;
        dinv[n0 + t] = rsqrtf((float)(own + 1));
    }
    ncur[t] = rowbase;
    __syncthreads();
    for (int e = t; e < cnt; e += 256) {
        int pe = ebuf[start + e];
        int slot = atomicAdd(&ncur[pe >> 20], 1);
        colarr[slot] = pe & 0xFFFFF;
    }
}

// ------- split W [K][N] fp32 -> fp16 hi/lo in MFMA FRAGMENT ORDER -------
__global__ __launch_bounds__(256) void split_wt_frag(const float* __restrict__ W,
                                                     _Float16* __restrict__ hi,
                                                     _Float16* __restrict__ lo,
                                                     int K, int N) {
    int idx = blockIdx.x * 256 + threadIdx.x;
    if (idx >= K * N) return;
    int NT = N >> 4;
    int j = idx & 7;
    int l = (idx >> 3) & 63;
    int f = idx >> 9;
    int nt = f % NT;
    int kc = f / NT;
    int k = kc * 32 + (l >> 4) * 8 + j;
    int n = nt * 16 + (l & 15);
    float v = W[k * N + n];
    _Float16 h = (_Float16)v;
    hi[idx] = h;
    lo[idx] = (_Float16)(v - (float)h);
}

// ---------------- fp16 MFMA GEMM v2: pipelined, A direct-to-reg ----------------
// Structural changes vs v1 (which stalled at MfmaUtil 7%, 16us per k-step):
//  - A tile never touches LDS: each element of the old Ah[] was written once and
//    read exactly once (zero reuse), so it was pure overhead + barrier coupling.
//    Each lane now loads its own fragment rows global->VGPR and converts in-reg.
//  - One-iteration A prefetch: loads for step t+1 issue BEFORE the MFMA cluster
//    of step t, so the end-of-iter vmcnt(0) drain lands after a compute phase.
//  - B double-buffered in LDS (K-step 32 => 2x(NT KB hi + NT KB lo)), staged
//    with global_load_lds width-16; exactly ONE __syncthreads per k-step
//    (guide T3 minimum 2-phase template).
template <int BN, int KTOT, bool AFP16>
__global__ __launch_bounds__(256, 4) void gemm_f16(const void* __restrict__ Araw,
                                                   const _Float16* __restrict__ Bh_g,
                                                   const _Float16* __restrict__ Bl_g,
                                                   const float* __restrict__ dinv,
                                                   _Float16* __restrict__ C, int M) {
    constexpr int NT = BN / 16;        // 8 (gemm1) or 4 (gemm2)
    constexpr int NK = KTOT / 32;      // 8 or 4 k-steps
    constexpr int TILE = NT * 512;     // halves per k-step per (hi|lo)
    constexpr int FPW = NT / 4;        // 1KB async chunks per wave per (hi|lo)
    __shared__ _Float16 Bsh[2][TILE];
    __shared__ _Float16 Bsl[2][TILE];

    const int tid = threadIdx.x;
    const int wave = tid >> 6;
    const int lane = tid & 63;
    const int lm = lane & 15;
    const int q = lane >> 4;
    const int m0 = blockIdx.x * 128;

    // rows this lane owns for the A fragments (mt = 0,1)
    const int r0 = m0 + wave * 32 + lm;
    const int r1 = r0 + 16;
    const bool vr0 = r0 < M;
    const bool vr1 = r1 < M;

    const float* Af = (const float*)Araw;
    const _Float16* Ah16 = (const _Float16*)Araw;

    f32x4 acc[2][NT];
#pragma unroll
    for (int a = 0; a < 2; ++a)
#pragma unroll
        for (int b = 0; b < NT; ++b) acc[a][b] = (f32x4){0.f, 0.f, 0.f, 0.f};

    // A prefetch registers (static indices only)
    float4 pa0, pa1, pa2, pa3;   // fp32 path: rows r0,r0 / r1,r1
    uint4 ph0, ph1;              // fp16 path: rows r0 / r1

#define STAGE_B(kc_, b_)                                                          \
    do {                                                                          \
        _Pragma("unroll")                                                         \
        for (int i_ = 0; i_ < FPW; ++i_) {                                        \
            int f_ = wave * FPW + i_;                                             \
            async_copy16(&Bsh[b_][f_ * 512 + lane * 8],                           \
                         Bh_g + (size_t)(kc_) * TILE + f_ * 512 + lane * 8);      \
            async_copy16(&Bsl[b_][f_ * 512 + lane * 8],                           \
                         Bl_g + (size_t)(kc_) * TILE + f_ * 512 + lane * 8);      \
        }                                                                         \
    } while (0)

#define LOAD_A(t_)                                                                \
    do {                                                                          \
        const int k_ = (t_) * 32 + q * 8;                                         \
        if (AFP16) {                                                              \
            ph0 = vr0 ? *(const uint4*)&Ah16[(size_t)r0 * KTOT + k_]              \
                      : make_uint4(0u, 0u, 0u, 0u);                               \
            ph1 = vr1 ? *(const uint4*)&Ah16[(size_t)r1 * KTOT + k_]              \
                      : make_uint4(0u, 0u, 0u, 0u);                               \
        } else {                                                                  \
            float4 z_ = make_float4(0.f, 0.f, 0.f, 0.f);                          \
            pa0 = vr0 ? *(const float4*)&Af[(size_t)r0 * KTOT + k_] : z_;         \
            pa1 = vr0 ? *(const float4*)&Af[(size_t)r0 * KTOT + k_ + 4] : z_;     \
            pa2 = vr1 ? *(const float4*)&Af[(size_t)r1 * KTOT + k_] : z_;         \
            pa3 = vr1 ? *(const float4*)&Af[(size_t)r1 * KTOT + k_ + 4] : z_;     \
        }                                                                         \
    } while (0)

    // prologue: stage step 0 B, issue step 0 A, drain
    STAGE_B(0, 0);
    LOAD_A(0);
    __syncthreads();

#pragma unroll
    for (int t = 0; t < NK; ++t) {
        const int b = t & 1;
        // issue next step's B tile into the other buffer (latency hidden by MFMA)
        if (t + 1 < NK) STAGE_B(t + 1, b ^ 1);

        // convert current A regs -> fragments (frees prefetch regs)
        f16x8 a0, a1;
        if (AFP16) {
            a0 = *(f16x8*)&ph0;
            a1 = *(f16x8*)&ph1;
        } else {
            a0[0] = (_Float16)pa0.x; a0[1] = (_Float16)pa0.y;
            a0[2] = (_Float16)pa0.z; a0[3] = (_Float16)pa0.w;
            a0[4] = (_Float16)pa1.x; a0[5] = (_Float16)pa1.y;
            a0[6] = (_Float16)pa1.z; a0[7] = (_Float16)pa1.w;
            a1[0] = (_Float16)pa2.x; a1[1] = (_Float16)pa2.y;
            a1[2] = (_Float16)pa2.z; a1[3] = (_Float16)pa2.w;
            a1[4] = (_Float16)pa3.x; a1[5] = (_Float16)pa3.y;
            a1[6] = (_Float16)pa3.z; a1[7] = (_Float16)pa3.w;
        }
        // issue next step's A loads (complete during MFMA cluster below)
        if (t + 1 < NK) LOAD_A(t + 1);

#pragma unroll
        for (int nt = 0; nt < NT; ++nt) {
            f16x8 bh = *(const f16x8*)&Bsh[b][nt * 512 + lane * 8];
            f16x8 bl = *(const f16x8*)&Bsl[b][nt * 512 + lane * 8];
            acc[0][nt] = __builtin_amdgcn_mfma_f32_16x16x32_f16(a0, bh, acc[0][nt], 0, 0, 0);
            acc[0][nt] = __builtin_amdgcn_mfma_f32_16x16x32_f16(a0, bl, acc[0][nt], 0, 0, 0);
            acc[1][nt] = __builtin_amdgcn_mfma_f32_16x16x32_f16(a1, bh, acc[1][nt], 0, 0, 0);
            acc[1][nt] = __builtin_amdgcn_mfma_f32_16x16x32_f16(a1, bl, acc[1][nt], 0, 0, 0);
        }
        // single barrier per k-step: waits arrival of B(t+1)+A(t+1) (vmcnt) and
        // guards buffer reuse (all ds_reads of buf b done before restage at t+2)
        if (t + 1 < NK) __syncthreads();
    }
#undef STAGE_B
#undef LOAD_A

#pragma unroll
    for (int mt = 0; mt < 2; ++mt) {
#pragma unroll
        for (int i = 0; i < 4; ++i) {
            int r = m0 + wave * 32 + mt * 16 + q * 4 + i;
            if (r < M) {
                float dv = dinv[r];
#pragma unroll
                for (int nt = 0; nt < NT; ++nt) {
                    C[(size_t)r * BN + nt * 16 + lm] = (_Float16)(acc[mt][nt][i] * dv);
                }
            }
        }
    }
}

// ---------------- aggregation v3: uint4 gathers, masked remainders ----------------
__device__ __forceinline__ void acc8(float* a, uint4 v) {
    float2 f0 = __half22float2(*(const __half2*)&v.x);
    float2 f1 = __half22float2(*(const __half2*)&v.y);
    float2 f2 = __half22float2(*(const __half2*)&v.z);
    float2 f3 = __half22float2(*(const __half2*)&v.w);
    a[0] += f0.x; a[1] += f0.y; a[2] += f1.x; a[3] += f1.y;
    a[4] += f2.x; a[5] += f2.y; a[6] += f3.x; a[7] += f3.y;
}

// 128 ch: wave per node; 4 groups of 16 lanes -> 4 edges per load instruction
// (1 KB/inst). 8 fp16 channels per lane. Butterfly xor16+xor32; sel==0 stores fp16.
__global__ __launch_bounds__(256) void agg128(const _Float16* __restrict__ g,
                                              const int* __restrict__ rowptr,
                                              const int* __restrict__ colarr,
                                              const float* __restrict__ dinv,
                                              const float* __restrict__ bias,
                                              _Float16* __restrict__ out, int n) {
    int node = blockIdx.x * 4 + (threadIdx.x >> 6);
    int lane = threadIdx.x & 63;
    if (node >= n) return;
    int sel = lane >> 4;        // 0..3
    int co = (lane & 15) << 3;  // 8 fp16 channels

    int beg = rowptr[node];
    int end = rowptr[node + 1];

    float a[8] = {0.f, 0.f, 0.f, 0.f, 0.f, 0.f, 0.f, 0.f};
    if (sel == 0) acc8(a, *(const uint4*)&g[(node << 7) + co]);  // self loop

    int p = beg;
    for (; p + 16 <= end; p += 16) {
        int r0 = colarr[p + sel];
        int r1 = colarr[p + 4 + sel];
        int r2 = colarr[p + 8 + sel];
        int r3 = colarr[p + 12 + sel];
        uint4 v0 = *(const uint4*)&g[(r0 << 7) + co];
        uint4 v1 = *(const uint4*)&g[(r1 << 7) + co];
        uint4 v2 = *(const uint4*)&g[(r2 << 7) + co];
        uint4 v3 = *(const uint4*)&g[(r3 << 7) + co];
        acc8(a, v0); acc8(a, v1); acc8(a, v2); acc8(a, v3);
    }
    for (; p + 4 <= end; p += 4) {
        int r = colarr[p + sel];
        acc8(a, *(const uint4*)&g[(r << 7) + co]);
    }
    int rem = end - p;
    if (sel < rem) {
        int r = colarr[p + sel];
        acc8(a, *(const uint4*)&g[(r << 7) + co]);
    }

#pragma unroll
    for (int i = 0; i < 8; ++i) {
        a[i] += __shfl(a[i], lane ^ 16);
        a[i] += __shfl(a[i], lane ^ 32);
    }

    if (sel == 0) {
        float dv = dinv[node];
        float4 b0 = *(const float4*)&bias[co];
        float4 b1 = *(const float4*)&bias[co + 4];
        float o0 = fmaxf(fmaf(a[0], dv, b0.x), 0.f);
        float o1 = fmaxf(fmaf(a[1], dv, b0.y), 0.f);
        float o2 = fmaxf(fmaf(a[2], dv, b0.z), 0.f);
        float o3 = fmaxf(fmaf(a[3], dv, b0.w), 0.f);
        float o4 = fmaxf(fmaf(a[4], dv, b1.x), 0.f);
        float o5 = fmaxf(fmaf(a[5], dv, b1.y), 0.f);
        float o6 = fmaxf(fmaf(a[6], dv, b1.z), 0.f);
        float o7 = fmaxf(fmaf(a[7], dv, b1.w), 0.f);
        __half2 h0 = __floats2half2_rn(o0, o1);
        __half2 h1 = __floats2half2_rn(o2, o3);
        __half2 h2 = __floats2half2_rn(o4, o5);
        __half2 h3 = __floats2half2_rn(o6, o7);
        uint4 pk = make_uint4(*(unsigned*)&h0, *(unsigned*)&h1,
                              *(unsigned*)&h2, *(unsigned*)&h3);
        *(uint4*)&out[(node << 7) + co] = pk;
    }
}

// 64 ch: wave per node; 8 groups of 8 lanes -> 8 edges per load instruction.
// 8 fp16 channels per lane. Butterfly xor8+xor16+xor32; sel==0 stores fp32.
__global__ __launch_bounds__(256) void agg64(const _Float16* __restrict__ g,
                                             const int* __restrict__ rowptr,
                                             const int* __restrict__ colarr,
                                             const float* __restrict__ dinv,
                                             const float* __restrict__ bias,
                                             float* __restrict__ out, int n) {
    int node = blockIdx.x * 4 + (threadIdx.x >> 6);
    int lane = threadIdx.x & 63;
    if (node >= n) return;
    int sel = lane >> 3;       // 0..7
    int co = (lane & 7) << 3;  // 8 fp16 channels

    int beg = rowptr[node];
    int end = rowptr[node + 1];

    float a[8] = {0.f, 0.f, 0.f, 0.f, 0.f, 0.f, 0.f, 0.f};
    if (sel == 0) acc8(a, *(const uint4*)&g[(node << 6) + co]);  // self loop

    int p = beg;
    for (; p + 16 <= end; p += 16) {
        int r0 = colarr[p + sel];
        int r1 = colarr[p + 8 + sel];
        uint4 v0 = *(const uint4*)&g[(r0 << 6) + co];
        uint4 v1 = *(const uint4*)&g[(r1 << 6) + co];
        acc8(a, v0); acc8(a, v1);
    }
    for (; p + 8 <= end; p += 8) {
        int r = colarr[p + sel];
        acc8(a, *(const uint4*)&g[(r << 6) + co]);
    }
    int rem = end - p;
    if (sel < rem) {
        int r = colarr[p + sel];
        acc8(a, *(const uint4*)&g[(r << 6) + co]);
    }

#pragma unroll
    for (int i = 0; i < 8; ++i) {
        a[i] += __shfl(a[i], lane ^ 8);
        a[i] += __shfl(a[i], lane ^ 16);
        a[i] += __shfl(a[i], lane ^ 32);
    }

    if (sel == 0) {
        float dv = dinv[node];
        float4 b0 = *(const float4*)&bias[co];
        float4 b1 = *(const float4*)&bias[co + 4];
        float4 oA, oB;
        oA.x = fmaxf(fmaf(a[0], dv, b0.x), 0.f);
        oA.y = fmaxf(fmaf(a[1], dv, b0.y), 0.f);
        oA.z = fmaxf(fmaf(a[2], dv, b0.z), 0.f);
        oA.w = fmaxf(fmaf(a[3], dv, b0.w), 0.f);
        oB.x = fmaxf(fmaf(a[4], dv, b1.x), 0.f);
        oB.y = fmaxf(fmaf(a[5], dv, b1.y), 0.f);
        oB.z = fmaxf(fmaf(a[6], dv, b1.z), 0.f);
        oB.w = fmaxf(fmaf(a[7], dv, b1.w), 0.f);
        *(float4*)&out[(node << 6) + co] = oA;
        *(float4*)&out[(node << 6) + co + 4] = oB;
    }
}

extern "C" void kernel_launch(void* const* d_in, const int* in_sizes, int n_in,
                              void* d_out, int out_size, void* d_ws, size_t ws_size,
                              hipStream_t stream) {
    const float* x  = (const float*)d_in[0];
    const int*   ei = (const int*)d_in[1];
    const float* W1 = (const float*)d_in[2];
    const float* b1 = (const float*)d_in[3];
    const float* W2 = (const float*)d_in[4];
    const float* b2 = (const float*)d_in[5];
    float* out = (float*)d_out;

    const int E = in_sizes[1] / 2;
    const int H1 = in_sizes[3];                 // 128
    const int K1 = in_sizes[2] / H1;            // 256
    const int N = in_sizes[0] / K1;             // 100000
    const int H2 = in_sizes[4] / H1;            // 64
    const int* src = ei;
    const int* dst = ei + E;
    const int NB = (N + 255) >> 8;

    char* ws = (char*)d_ws;
    _Float16* w1th   = (_Float16*)(ws + OFF_W1TH);
    _Float16* w1tl   = (_Float16*)(ws + OFF_W1TL);
    _Float16* w2th   = (_Float16*)(ws + OFF_W2TH);
    _Float16* w2tl   = (_Float16*)(ws + OFF_W2TL);
    int*      bcnt   = (int*)(ws + OFF_BCNT);
    int*      bbase  = (int*)(ws + OFF_BBASE);
    int*      bcur   = (int*)(ws + OFF_BCUR);
    int*      rowptr = (int*)(ws + OFF_ROWPTR);
    float*    dinv   = (float*)(ws + OFF_DINV);
    int*      colarr = (int*)(ws + OFF_COL);
    int*      ebuf   = (int*)(ws + OFF_EBUF);
    _Float16* h1g    = (_Float16*)(ws + OFF_H1G);
    _Float16* h1out  = (_Float16*)(ws + OFF_H1OUT);
    _Float16* h2g    = (_Float16*)(ws + OFF_H1G);   // reuse

    hipMemsetAsync(bcnt, 0, 512 * sizeof(int), stream);
    bincount<<<256, 256, 0, stream>>>(dst, bcnt, E);
    bscan<<<1, 512, 0, stream>>>(bcnt, bbase, bcur, rowptr, NB, N, E);
    binscatter<<<(E + CHUNK - 1) / CHUNK, 256, 0, stream>>>(src, dst, bcur, ebuf, E);
    buildcsr<<<NB, 256, 0, stream>>>(ebuf, bbase, bcnt, rowptr, colarr, dinv, N);

    split_wt_frag<<<(K1 * H1 + 255) / 256, 256, 0, stream>>>(W1, w1th, w1tl, K1, H1);
    split_wt_frag<<<(H1 * H2 + 255) / 256, 256, 0, stream>>>(W2, w2th, w2tl, H1, H2);

    // layer 1
    gemm_f16<128, 256, false><<<(N + 127) / 128, 256, 0, stream>>>(x, w1th, w1tl, dinv, h1g, N);
    agg128<<<(N + 3) / 4, 256, 0, stream>>>(h1g, rowptr, colarr, dinv, b1, h1out, N);

    // layer 2
    gemm_f16<64, 128, true><<<(N + 127) / 128, 256, 0, stream>>>(h1out, w2th, w2tl, dinv, h2g, N);
    agg64<<<(N + 3) / 4, 256, 0, stream>>>(h2g, rowptr, colarr, dinv, b2, out, N);
}

// Round 2
// 417.093 us; speedup vs baseline: 1.0010x; 1.0010x over previous
//
#include <hip/hip_runtime.h>
#include <hip/hip_fp16.h>

// ---------------- problem constants ----------------
#define NNODES 100000

// ---------------- workspace layout (bytes) ----------------
#define OFF_W1TH     0UL            // _Float16[256*128] frag-order = 65536
#define OFF_W1TL     65536UL        // _Float16[256*128]
#define OFF_W2TH     131072UL       // _Float16[128*64] = 16384
#define OFF_W2TL     147456UL       // _Float16[128*64] -> ends 163840
#define OFF_BCNT     163840UL       // int[512]
#define OFF_BBASE    165888UL       // int[512]
#define OFF_BCUR     167936UL       // int[512] -> ends 169984
#define OFF_ROWPTR   400128UL       // int[100001]
#define OFF_DINV     1200640UL      // float[100000]
#define OFF_COL      1605632UL      // int[1600000]  -> ends 8005632
#define OFF_EBUF     8005632UL      // int[1600000] = 6.4MB (overlaps h1g; dead before gemm1)
#define OFF_H1G      8005632UL      // half[100000*128] = 25.6MB -> ends 33605632
#define OFF_H1OUT    59205632UL     // half[100000*128] = 25.6MB -> ends 84805632
// h2g (half[100000*64]) reuses OFF_H1G (h1g dead after agg1)

typedef __attribute__((ext_vector_type(8))) _Float16 f16x8;
typedef __attribute__((ext_vector_type(4))) float f32x4;

// async global->LDS 16B per lane (dest = wave-uniform base + lane*16)
__device__ __forceinline__ void async_copy16(void* lds, const void* g) {
    __builtin_amdgcn_global_load_lds(
        (const __attribute__((address_space(1))) unsigned*)g,
        (__attribute__((address_space(3))) unsigned*)lds, 16, 0, 0);
}

// =========== CSR build via 2-level counting sort (bucket = dst>>8) ===========
__global__ __launch_bounds__(256) void bincount(const int* __restrict__ dst,
                                                int* __restrict__ bcnt, int E) {
    __shared__ int lc[512];
    int t = threadIdx.x;
    lc[t] = 0; lc[t + 256] = 0;
    __syncthreads();
    for (int e = blockIdx.x * 256 + t; e < E; e += gridDim.x * 256)
        atomicAdd(&lc[dst[e] >> 8], 1);
    __syncthreads();
    if (lc[t]) atomicAdd(&bcnt[t], lc[t]);
    if (lc[t + 256]) atomicAdd(&bcnt[t + 256], lc[t + 256]);
}

__global__ __launch_bounds__(512) void bscan(const int* __restrict__ bcnt,
                                             int* __restrict__ bbase,
                                             int* __restrict__ bcur,
                                             int* __restrict__ rowptr,
                                             int NB, int N, int E) {
    __shared__ int s[512];
    int t = threadIdx.x;
    int v = (t < NB) ? bcnt[t] : 0;
    s[t] = v;
    __syncthreads();
    for (int off = 1; off < 512; off <<= 1) {
        int add = (t >= off) ? s[t - off] : 0;
        __syncthreads();
        s[t] += add;
        __syncthreads();
    }
    if (t < NB) {
        int ex = s[t] - v;
        bbase[t] = ex;
        bcur[t] = ex;
    }
    if (t == 0) rowptr[N] = E;
}

// Phase C: bucket-grouped scatter. Packs (src | localdst<<20) into one int.
#define CHUNK 8192
__global__ __launch_bounds__(256) void binscatter(const int* __restrict__ src,
                                                  const int* __restrict__ dst,
                                                  int* __restrict__ bcur,
                                                  int* __restrict__ ebuf, int E) {
    __shared__ int lc[512];
    __shared__ int gb[512];
    int t = threadIdx.x;
    lc[t] = 0; lc[t + 256] = 0;
    __syncthreads();
    int base = blockIdx.x * CHUNK;
    int rb[32];
#pragma unroll
    for (int i = 0; i < 32; ++i) {
        int e = base + i * 256 + t;
        if (e < E) {
            int b = dst[e] >> 8;
            rb[i] = (b << 13) | atomicAdd(&lc[b], 1);  // rank < 8192 fits 13 bits
        } else rb[i] = -1;
    }
    __syncthreads();
    if (lc[t]) gb[t] = atomicAdd(&bcur[t], lc[t]);
    if (lc[t + 256]) gb[t + 256] = atomicAdd(&bcur[t + 256], lc[t + 256]);
    __syncthreads();
#pragma unroll
    for (int i = 0; i < 32; ++i) {
        if (rb[i] >= 0) {
            int e = base + i * 256 + t;
            int b = rb[i] >> 13, r = rb[i] & 8191;
            ebuf[gb[b] + r] = src[e] | ((dst[e] & 255) << 20);
        }
    }
}

__global__ __launch_bounds__(256) void buildcsr(const int* __restrict__ ebuf,
                                                const int* __restrict__ bbase,
                                                const int* __restrict__ bcnt,
                                                int* __restrict__ rowptr,
                                                int* __restrict__ colarr,
                                                float* __restrict__ dinv, int N) {
    int b = blockIdx.x;
    int t = threadIdx.x;
    int start = bbase[b];
    int cnt = bcnt[b];
    __shared__ int nc[256];
    __shared__ int s[256];
    __shared__ int ncur[256];
    nc[t] = 0;
    __syncthreads();
    for (int e = t; e < cnt; e += 256) atomicAdd(&nc[ebuf[start + e] >> 20], 1);
    __syncthreads();
    int own = nc[t];
    s[t] = own;
    __syncthreads();
    for (int off = 1; off < 256; off <<= 1) {
        int add = (t >= off) ? s[t - off] : 0;
        __syncthreads();
        s[t] += add;
        __syncthreads();
    }
    int rowbase = start + s[t] - own;
    int n0 = b << 8;
    if (n0 + t < N) {
        rowptr[n0 + t] = rowbase;
        dinv[n0 + t] = rsqrtf((float)(own + 1));
    }
    ncur[t] = rowbase;
    __syncthreads();
    for (int e = t; e < cnt; e += 256) {
        int pe = ebuf[start + e];
        int slot = atomicAdd(&ncur[pe >> 20], 1);
        colarr[slot] = pe & 0xFFFFF;
    }
}

// ------- split W [K][N] fp32 -> fp16 hi/lo in MFMA FRAGMENT ORDER -------
__global__ __launch_bounds__(256) void split_wt_frag(const float* __restrict__ W,
                                                     _Float16* __restrict__ hi,
                                                     _Float16* __restrict__ lo,
                                                     int K, int N) {
    int idx = blockIdx.x * 256 + threadIdx.x;
    if (idx >= K * N) return;
    int NT = N >> 4;
    int j = idx & 7;
    int l = (idx >> 3) & 63;
    int f = idx >> 9;
    int nt = f % NT;
    int kc = f / NT;
    int k = kc * 32 + (l >> 4) * 8 + j;
    int n = nt * 16 + (l & 15);
    float v = W[k * N + n];
    _Float16 h = (_Float16)v;
    hi[idx] = h;
    lo[idx] = (_Float16)(v - (float)h);
}

// ---------------- fp16 MFMA GEMM v3: pipelined, A direct-to-reg ----------------
// v2 -> v3 post-mortem: v2's __launch_bounds__(256,4) capped the unified reg
// file at 128/lane; acc alone is 64 (AGPR side), so the allocator spilled
// ~16 dwords/thread to scratch (visible as +14MB WRITE_SIZE / +7MB FETCH_SIZE,
// VGPR_Count 64). Scratch latency serialized everything (MfmaUtil 4.6%).
// Fix: (256,3) -> cap ~170 regs, matching the ~164-reg live set. Structure
// (A never in LDS, B double-buffered via global_load_lds, one barrier per
// k-step, one-step A prefetch) unchanged.
template <int BN, int KTOT, bool AFP16>
__global__ __launch_bounds__(256, 3) void gemm_f16(const void* __restrict__ Araw,
                                                   const _Float16* __restrict__ Bh_g,
                                                   const _Float16* __restrict__ Bl_g,
                                                   const float* __restrict__ dinv,
                                                   _Float16* __restrict__ C, int M) {
    constexpr int NT = BN / 16;        // 8 (gemm1) or 4 (gemm2)
    constexpr int NK = KTOT / 32;      // 8 or 4 k-steps
    constexpr int TILE = NT * 512;     // halves per k-step per (hi|lo)
    constexpr int FPW = NT / 4;        // 1KB async chunks per wave per (hi|lo)
    __shared__ _Float16 Bsh[2][TILE];
    __shared__ _Float16 Bsl[2][TILE];

    const int tid = threadIdx.x;
    const int wave = tid >> 6;
    const int lane = tid & 63;
    const int lm = lane & 15;
    const int q = lane >> 4;
    const int m0 = blockIdx.x * 128;

    // rows this lane owns for the A fragments (mt = 0,1)
    const int r0 = m0 + wave * 32 + lm;
    const int r1 = r0 + 16;
    const bool vr0 = r0 < M;
    const bool vr1 = r1 < M;

    const float* Af = (const float*)Araw;
    const _Float16* Ah16 = (const _Float16*)Araw;

    f32x4 acc[2][NT];
#pragma unroll
    for (int a = 0; a < 2; ++a)
#pragma unroll
        for (int b = 0; b < NT; ++b) acc[a][b] = (f32x4){0.f, 0.f, 0.f, 0.f};

    // A prefetch registers (static indices only)
    float4 pa0, pa1, pa2, pa3;   // fp32 path: rows r0,r0 / r1,r1
    uint4 ph0, ph1;              // fp16 path: rows r0 / r1

#define STAGE_B(kc_, b_)                                                          \
    do {                                                                          \
        _Pragma("unroll")                                                         \
        for (int i_ = 0; i_ < FPW; ++i_) {                                        \
            int f_ = wave * FPW + i_;                                             \
            async_copy16(&Bsh[b_][f_ * 512 + lane * 8],                           \
                         Bh_g + (size_t)(kc_) * TILE + f_ * 512 + lane * 8);      \
            async_copy16(&Bsl[b_][f_ * 512 + lane * 8],                           \
                         Bl_g + (size_t)(kc_) * TILE + f_ * 512 + lane * 8);      \
        }                                                                         \
    } while (0)

#define LOAD_A(t_)                                                                \
    do {                                                                          \
        const int k_ = (t_) * 32 + q * 8;                                         \
        if (AFP16) {                                                              \
            ph0 = vr0 ? *(const uint4*)&Ah16[(size_t)r0 * KTOT + k_]              \
                      : make_uint4(0u, 0u, 0u, 0u);                               \
            ph1 = vr1 ? *(const uint4*)&Ah16[(size_t)r1 * KTOT + k_]              \
                      : make_uint4(0u, 0u, 0u, 0u);                               \
        } else {                                                                  \
            float4 z_ = make_float4(0.f, 0.f, 0.f, 0.f);                          \
            pa0 = vr0 ? *(const float4*)&Af[(size_t)r0 * KTOT + k_] : z_;         \
            pa1 = vr0 ? *(const float4*)&Af[(size_t)r0 * KTOT + k_ + 4] : z_;     \
            pa2 = vr1 ? *(const float4*)&Af[(size_t)r1 * KTOT + k_] : z_;         \
            pa3 = vr1 ? *(const float4*)&Af[(size_t)r1 * KTOT + k_ + 4] : z_;     \
        }                                                                         \
    } while (0)

    // prologue: stage step 0 B, issue step 0 A, drain
    STAGE_B(0, 0);
    LOAD_A(0);
    __syncthreads();

#pragma unroll
    for (int t = 0; t < NK; ++t) {
        const int b = t & 1;
        // issue next step's B tile into the other buffer (latency hidden by MFMA)
        if (t + 1 < NK) STAGE_B(t + 1, b ^ 1);

        // convert current A regs -> fragments (frees prefetch regs)
        f16x8 a0, a1;
        if (AFP16) {
            a0 = *(f16x8*)&ph0;
            a1 = *(f16x8*)&ph1;
        } else {
            a0[0] = (_Float16)pa0.x; a0[1] = (_Float16)pa0.y;
            a0[2] = (_Float16)pa0.z; a0[3] = (_Float16)pa0.w;
            a0[4] = (_Float16)pa1.x; a0[5] = (_Float16)pa1.y;
            a0[6] = (_Float16)pa1.z; a0[7] = (_Float16)pa1.w;
            a1[0] = (_Float16)pa2.x; a1[1] = (_Float16)pa2.y;
            a1[2] = (_Float16)pa2.z; a1[3] = (_Float16)pa2.w;
            a1[4] = (_Float16)pa3.x; a1[5] = (_Float16)pa3.y;
            a1[6] = (_Float16)pa3.z; a1[7] = (_Float16)pa3.w;
        }
        // issue next step's A loads (complete during MFMA cluster below)
        if (t + 1 < NK) LOAD_A(t + 1);

#pragma unroll
        for (int nt = 0; nt < NT; ++nt) {
            f16x8 bh = *(const f16x8*)&Bsh[b][nt * 512 + lane * 8];
            f16x8 bl = *(const f16x8*)&Bsl[b][nt * 512 + lane * 8];
            acc[0][nt] = __builtin_amdgcn_mfma_f32_16x16x32_f16(a0, bh, acc[0][nt], 0, 0, 0);
            acc[0][nt] = __builtin_amdgcn_mfma_f32_16x16x32_f16(a0, bl, acc[0][nt], 0, 0, 0);
            acc[1][nt] = __builtin_amdgcn_mfma_f32_16x16x32_f16(a1, bh, acc[1][nt], 0, 0, 0);
            acc[1][nt] = __builtin_amdgcn_mfma_f32_16x16x32_f16(a1, bl, acc[1][nt], 0, 0, 0);
        }
        // single barrier per k-step: waits arrival of B(t+1)+A(t+1) (vmcnt) and
        // guards buffer reuse (all ds_reads of buf b done before restage at t+2)
        if (t + 1 < NK) __syncthreads();
    }
#undef STAGE_B
#undef LOAD_A

#pragma unroll
    for (int mt = 0; mt < 2; ++mt) {
#pragma unroll
        for (int i = 0; i < 4; ++i) {
            int r = m0 + wave * 32 + mt * 16 + q * 4 + i;
            if (r < M) {
                float dv = dinv[r];
#pragma unroll
                for (int nt = 0; nt < NT; ++nt) {
                    C[(size_t)r * BN + nt * 16 + lm] = (_Float16)(acc[mt][nt][i] * dv);
                }
            }
        }
    }
}

// ---------------- aggregation v3: uint4 gathers, masked remainders ----------------
__device__ __forceinline__ void acc8(float* a, uint4 v) {
    float2 f0 = __half22float2(*(const __half2*)&v.x);
    float2 f1 = __half22float2(*(const __half2*)&v.y);
    float2 f2 = __half22float2(*(const __half2*)&v.z);
    float2 f3 = __half22float2(*(const __half2*)&v.w);
    a[0] += f0.x; a[1] += f0.y; a[2] += f1.x; a[3] += f1.y;
    a[4] += f2.x; a[5] += f2.y; a[6] += f3.x; a[7] += f3.y;
}

// 128 ch: wave per node; 4 groups of 16 lanes -> 4 edges per load instruction
// (1 KB/inst). 8 fp16 channels per lane. Butterfly xor16+xor32; sel==0 stores fp16.
__global__ __launch_bounds__(256) void agg128(const _Float16* __restrict__ g,
                                              const int* __restrict__ rowptr,
                                              const int* __restrict__ colarr,
                                              const float* __restrict__ dinv,
                                              const float* __restrict__ bias,
                                              _Float16* __restrict__ out, int n) {
    int node = blockIdx.x * 4 + (threadIdx.x >> 6);
    int lane = threadIdx.x & 63;
    if (node >= n) return;
    int sel = lane >> 4;        // 0..3
    int co = (lane & 15) << 3;  // 8 fp16 channels

    int beg = rowptr[node];
    int end = rowptr[node + 1];

    float a[8] = {0.f, 0.f, 0.f, 0.f, 0.f, 0.f, 0.f, 0.f};
    if (sel == 0) acc8(a, *(const uint4*)&g[(node << 7) + co]);  // self loop

    int p = beg;
    for (; p + 16 <= end; p += 16) {
        int r0 = colarr[p + sel];
        int r1 = colarr[p + 4 + sel];
        int r2 = colarr[p + 8 + sel];
        int r3 = colarr[p + 12 + sel];
        uint4 v0 = *(const uint4*)&g[(r0 << 7) + co];
        uint4 v1 = *(const uint4*)&g[(r1 << 7) + co];
        uint4 v2 = *(const uint4*)&g[(r2 << 7) + co];
        uint4 v3 = *(const uint4*)&g[(r3 << 7) + co];
        acc8(a, v0); acc8(a, v1); acc8(a, v2); acc8(a, v3);
    }
    for (; p + 4 <= end; p += 4) {
        int r = colarr[p + sel];
        acc8(a, *(const uint4*)&g[(r << 7) + co]);
    }
    int rem = end - p;
    if (sel < rem) {
        int r = colarr[p + sel];
        acc8(a, *(const uint4*)&g[(r << 7) + co]);
    }

#pragma unroll
    for (int i = 0; i < 8; ++i) {
        a[i] += __shfl(a[i], lane ^ 16);
        a[i] += __shfl(a[i], lane ^ 32);
    }

    if (sel == 0) {
        float dv = dinv[node];
        float4 b0 = *(const float4*)&bias[co];
        float4 b1 = *(const float4*)&bias[co + 4];
        float o0 = fmaxf(fmaf(a[0], dv, b0.x), 0.f);
        float o1 = fmaxf(fmaf(a[1], dv, b0.y), 0.f);
        float o2 = fmaxf(fmaf(a[2], dv, b0.z), 0.f);
        float o3 = fmaxf(fmaf(a[3], dv, b0.w), 0.f);
        float o4 = fmaxf(fmaf(a[4], dv, b1.x), 0.f);
        float o5 = fmaxf(fmaf(a[5], dv, b1.y), 0.f);
        float o6 = fmaxf(fmaf(a[6], dv, b1.z), 0.f);
        float o7 = fmaxf(fmaf(a[7], dv, b1.w), 0.f);
        __half2 h0 = __floats2half2_rn(o0, o1);
        __half2 h1 = __floats2half2_rn(o2, o3);
        __half2 h2 = __floats2half2_rn(o4, o5);
        __half2 h3 = __floats2half2_rn(o6, o7);
        uint4 pk = make_uint4(*(unsigned*)&h0, *(unsigned*)&h1,
                              *(unsigned*)&h2, *(unsigned*)&h3);
        *(uint4*)&out[(node << 7) + co] = pk;
    }
}

// 64 ch: wave per node; 8 groups of 8 lanes -> 8 edges per load instruction.
// 8 fp16 channels per lane. Butterfly xor8+xor16+xor32; sel==0 stores fp32.
__global__ __launch_bounds__(256) void agg64(const _Float16* __restrict__ g,
                                             const int* __restrict__ rowptr,
                                             const int* __restrict__ colarr,
                                             const float* __restrict__ dinv,
                                             const float* __restrict__ bias,
                                             float* __restrict__ out, int n) {
    int node = blockIdx.x * 4 + (threadIdx.x >> 6);
    int lane = threadIdx.x & 63;
    if (node >= n) return;
    int sel = lane >> 3;       // 0..7
    int co = (lane & 7) << 3;  // 8 fp16 channels

    int beg = rowptr[node];
    int end = rowptr[node + 1];

    float a[8] = {0.f, 0.f, 0.f, 0.f, 0.f, 0.f, 0.f, 0.f};
    if (sel == 0) acc8(a, *(const uint4*)&g[(node << 6) + co]);  // self loop

    int p = beg;
    for (; p + 16 <= end; p += 16) {
        int r0 = colarr[p + sel];
        int r1 = colarr[p + 8 + sel];
        uint4 v0 = *(const uint4*)&g[(r0 << 6) + co];
        uint4 v1 = *(const uint4*)&g[(r1 << 6) + co];
        acc8(a, v0); acc8(a, v1);
    }
    for (; p + 8 <= end; p += 8) {
        int r = colarr[p + sel];
        acc8(a, *(const uint4*)&g[(r << 6) + co]);
    }
    int rem = end - p;
    if (sel < rem) {
        int r = colarr[p + sel];
        acc8(a, *(const uint4*)&g[(r << 6) + co]);
    }

#pragma unroll
    for (int i = 0; i < 8; ++i) {
        a[i] += __shfl(a[i], lane ^ 8);
        a[i] += __shfl(a[i], lane ^ 16);
        a[i] += __shfl(a[i], lane ^ 32);
    }

    if (sel == 0) {
        float dv = dinv[node];
        float4 b0 = *(const float4*)&bias[co];
        float4 b1 = *(const float4*)&bias[co + 4];
        float4 oA, oB;
        oA.x = fmaxf(fmaf(a[0], dv, b0.x), 0.f);
        oA.y = fmaxf(fmaf(a[1], dv, b0.y), 0.f);
        oA.z = fmaxf(fmaf(a[2], dv, b0.z), 0.f);
        oA.w = fmaxf(fmaf(a[3], dv, b0.w), 0.f);
        oB.x = fmaxf(fmaf(a[4], dv, b1.x), 0.f);
        oB.y = fmaxf(fmaf(a[5], dv, b1.y), 0.f);
        oB.z = fmaxf(fmaf(a[6], dv, b1.z), 0.f);
        oB.w = fmaxf(fmaf(a[7], dv, b1.w), 0.f);
        *(float4*)&out[(node << 6) + co] = oA;
        *(float4*)&out[(node << 6) + co + 4] = oB;
    }
}

extern "C" void kernel_launch(void* const* d_in, const int* in_sizes, int n_in,
                              void* d_out, int out_size, void* d_ws, size_t ws_size,
                              hipStream_t stream) {
    const float* x  = (const float*)d_in[0];
    const int*   ei = (const int*)d_in[1];
    const float* W1 = (const float*)d_in[2];
    const float* b1 = (const float*)d_in[3];
    const float* W2 = (const float*)d_in[4];
    const float* b2 = (const float*)d_in[5];
    float* out = (float*)d_out;

    const int E = in_sizes[1] / 2;
    const int H1 = in_sizes[3];                 // 128
    const int K1 = in_sizes[2] / H1;            // 256
    const int N = in_sizes[0] / K1;             // 100000
    const int H2 = in_sizes[4] / H1;            // 64
    const int* src = ei;
    const int* dst = ei + E;
    const int NB = (N + 255) >> 8;

    char* ws = (char*)d_ws;
    _Float16* w1th   = (_Float16*)(ws + OFF_W1TH);
    _Float16* w1tl   = (_Float16*)(ws + OFF_W1TL);
    _Float16* w2th   = (_Float16*)(ws + OFF_W2TH);
    _Float16* w2tl   = (_Float16*)(ws + OFF_W2TL);
    int*      bcnt   = (int*)(ws + OFF_BCNT);
    int*      bbase  = (int*)(ws + OFF_BBASE);
    int*      bcur   = (int*)(ws + OFF_BCUR);
    int*      rowptr = (int*)(ws + OFF_ROWPTR);
    float*    dinv   = (float*)(ws + OFF_DINV);
    int*      colarr = (int*)(ws + OFF_COL);
    int*      ebuf   = (int*)(ws + OFF_EBUF);
    _Float16* h1g    = (_Float16*)(ws + OFF_H1G);
    _Float16* h1out  = (_Float16*)(ws + OFF_H1OUT);
    _Float16* h2g    = (_Float16*)(ws + OFF_H1G);   // reuse

    hipMemsetAsync(bcnt, 0, 512 * sizeof(int), stream);
    bincount<<<256, 256, 0, stream>>>(dst, bcnt, E);
    bscan<<<1, 512, 0, stream>>>(bcnt, bbase, bcur, rowptr, NB, N, E);
    binscatter<<<(E + CHUNK - 1) / CHUNK, 256, 0, stream>>>(src, dst, bcur, ebuf, E);
    buildcsr<<<NB, 256, 0, stream>>>(ebuf, bbase, bcnt, rowptr, colarr, dinv, N);

    split_wt_frag<<<(K1 * H1 + 255) / 256, 256, 0, stream>>>(W1, w1th, w1tl, K1, H1);
    split_wt_frag<<<(H1 * H2 + 255) / 256, 256, 0, stream>>>(W2, w2th, w2tl, H1, H2);

    // layer 1
    gemm_f16<128, 256, false><<<(N + 127) / 128, 256, 0, stream>>>(x, w1th, w1tl, dinv, h1g, N);
    agg128<<<(N + 3) / 4, 256, 0, stream>>>(h1g, rowptr, colarr, dinv, b1, h1out, N);

    // layer 2
    gemm_f16<64, 128, true><<<(N + 127) / 128, 256, 0, stream>>>(h1out, w2th, w2tl, dinv, h2g, N);
    agg64<<<(N + 3) / 4, 256, 0, stream>>>(h2g, rowptr, colarr, dinv, b2, out, N);
}